// Round 10
// baseline (140.610 us; speedup 1.0000x reference)
//
#include <hip/hip_runtime.h>
#include <stdint.h>

#define N 4096
#define BM 256
#define BK 64
#define TILES 16
#define NSPLIT 359   // bi>=4 chunk items: sum (16-bi)*ceil((bi+1)/2)
#define NUP 417      // + whole tiles bi 3..0 (13+14+15+16)
#define NITEMS 537   // + 120 lower zero tiles
#define NWORKERS 256 // 1 block/CU (128KB LDS)
#define CHUNK 8      // k64-steps per split item (K-span 512)

typedef __attribute__((ext_vector_type(8))) short s16x8;
typedef __attribute__((ext_vector_type(4))) float f32x4;

// round-to-nearest-even fp32 -> bf16
__device__ __forceinline__ unsigned short f2bf(float f) {
  union { float f; unsigned int u; } c; c.f = f;
  unsigned int u = c.u;
  unsigned int r = (u + 0x7fffu + ((u >> 16) & 1u)) >> 16;
  return (unsigned short)r;
}

__device__ __forceinline__ void gld16(const void* g, void* l) {
  __builtin_amdgcn_global_load_lds(
      (const __attribute__((address_space(1))) unsigned int*)g,
      (__attribute__((address_space(3))) unsigned int*)l,
      16, 0, 0);
}

// Fused prepass (C-zero moved into trigemm queue):
//  [0,4096):      B -> triu-masked bf16 transposed (256-granular k-bound)
//  [4096,12288):  A -> tril-masked bf16 (256-granular k-bound)
// Block 0 zeroes the work counter + 256 per-tile store flags.
__global__ void prep(const float* __restrict__ A, const float* __restrict__ B,
                     unsigned short* __restrict__ Abf, unsigned short* __restrict__ Bt,
                     int* __restrict__ cnt, int* __restrict__ flags) {
  int bid = blockIdx.x;
  int t = threadIdx.x;
  if (bid == 0) {
    if (t == 0) *cnt = 0;
    flags[t] = 0;                                 // 256 flags, 256 threads
  }
  if (bid < 4096) {
    // ---- B path: 64x64 tile transpose with triu mask ----
    int k0 = (bid & 63) * 64;
    int c0 = (bid >> 6) * 64;
    int cj = c0 >> 8;                             // 256-col tile
    if (k0 >= ((cj + 1) << 8)) return;            // never read by trigemm
    if (k0 > c0 + 63) {
      ushort4 z = make_ushort4(0, 0, 0, 0);
#pragma unroll
      for (int p = 0; p < 4; p++) {
        int cl = p * 16 + (t >> 4);
        int kl = (t & 15) * 4;
        *reinterpret_cast<ushort4*>(Bt + (long)(c0 + cl) * N + k0 + kl) = z;
      }
      return;
    }
    __shared__ unsigned short lds[64][72];        // +8 pad breaks transpose conflicts
#pragma unroll
    for (int p = 0; p < 4; p++) {
      int kl = p * 16 + (t >> 4);
      int cl = (t & 15) * 4;
      float4 v = *reinterpret_cast<const float4*>(B + (long)(k0 + kl) * N + c0 + cl);
      float vs[4] = {v.x, v.y, v.z, v.w};
#pragma unroll
      for (int i = 0; i < 4; i++)
        lds[kl][cl + i] = (k0 + kl <= c0 + cl + i) ? f2bf(vs[i]) : (unsigned short)0;
    }
    __syncthreads();
#pragma unroll
    for (int p = 0; p < 4; p++) {
      int cl = p * 16 + (t >> 4);
      int kl = (t & 15) * 4;
      ushort4 o;
      o.x = lds[kl + 0][cl]; o.y = lds[kl + 1][cl];
      o.z = lds[kl + 2][cl]; o.w = lds[kl + 3][cl];
      *reinterpret_cast<ushort4*>(Bt + (long)(c0 + cl) * N + k0 + kl) = o;
    }
  } else {
    // ---- A path: one block = half a row (2048 elems), 8 elems/thread ----
    long base = (long)(bid - 4096) * 2048 + (long)t * 8;
    int row = (int)(base >> 12);
    int k0 = (int)(base & 4095);
    int bound = ((row >> 8) + 1) << 8;            // 256-granular: first k never read
    if (k0 >= bound) return;
    if (k0 > row) {
      uint4 z = make_uint4(0u, 0u, 0u, 0u);
      *reinterpret_cast<uint4*>(Abf + base) = z;
      return;
    }
    const float4* src = reinterpret_cast<const float4*>(A + base);
    float4 v0 = src[0], v1 = src[1];
    float vs[8] = {v0.x, v0.y, v0.z, v0.w, v1.x, v1.y, v1.z, v1.w};
    unsigned int w[4];
#pragma unroll
    for (int i = 0; i < 4; i++) {
      unsigned int lo = (k0 + 2*i     <= row) ? f2bf(vs[2*i])     : 0u;
      unsigned int hi = (k0 + 2*i + 1 <= row) ? f2bf(vs[2*i + 1]) : 0u;
      w[i] = lo | (hi << 16);
    }
    uint4 o; o.x = w[0]; o.y = w[1]; o.z = w[2]; o.w = w[3];
    *reinterpret_cast<uint4*>(Abf + base) = o;
  }
}

// Triangular bf16 MFMA GEMM, 256x256 tile, 8-wave, 4-phase K-loop (R8 body,
// HW-verified waits). Split-K queue (CHUNK=8) + store-then-flag epilogue.
__global__ __launch_bounds__(512, 2) void trigemm(
    const unsigned short* __restrict__ Abf,
    const unsigned short* __restrict__ Bt,
    float* __restrict__ C, int* __restrict__ cnt, int* __restrict__ flags) {
  __shared__ unsigned short lA[2][BM * BK];  // 64 KB, XOR-swizzled rows of 128B
  __shared__ unsigned short lB[2][BM * BK];  // 64 KB
  __shared__ int sh;

  int t = threadIdx.x;
  int lane = t & 63, wave = t >> 6;
  int wr = wave >> 2, wc = wave & 3;          // 2M x 4N wave grid
  int l15 = lane & 15, l4 = lane >> 4;
  int sw7 = l15 & 7;
  int c0w = (l4 ^ sw7) * 8;                   // swizzled chunk, kk=0
  int c1w = ((4 + l4) ^ sw7) * 8;             // swizzled chunk, kk=1

  // staging: thread t -> row r (0..63 within 64-row piece), 16B chunk ck
  int r = t >> 3, ck = t & 7;
  int cks = ck ^ (r & 7);                     // inverse-swizzled source chunk
  unsigned short* dA = &lA[0][0] + r * BK + ck * 8;  // linear: base + t*16B
  unsigned short* dB = &lB[0][0] + r * BK + ck * 8;

#define STA(buf, h, j, kt) gld16(gA + (long)((h)*128 + (j)*64) * N + (long)(kt) * BK, \
                                 dA + (buf) * (BM * BK) + ((h)*128 + (j)*64) * BK)
#define STB(buf, h, j, kt) gld16(gB + (long)((h)*128 + (j)*64) * N + (long)(kt) * BK, \
                                 dB + (buf) * (BM * BK) + ((h)*128 + (j)*64) * BK)
#define LDA(mh, mi, kk) (*reinterpret_cast<const s16x8*>( \
    &bufA[(wr * 128 + (mh) * 64 + (mi) * 16 + l15) * BK + ((kk) ? c1w : c0w)]))
#define LDB(nh, ni, kk) (*reinterpret_cast<const s16x8*>( \
    &bufB[(wc * 64 + (nh) * 32 + (ni) * 16 + l15) * BK + ((kk) ? c1w : c0w)]))
#define MMQ(mh, nh)                                                          \
  __builtin_amdgcn_s_setprio(1);                                             \
  _Pragma("unroll") for (int mi = 0; mi < 4; mi++)                           \
  _Pragma("unroll") for (int ni = 0; ni < 2; ni++)                           \
  _Pragma("unroll") for (int kk = 0; kk < 2; kk++)                           \
    acc[(mh)*4 + mi][(nh)*2 + ni] = __builtin_amdgcn_mfma_f32_16x16x32_bf16( \
        af[mi][kk], bf[ni][kk], acc[(mh)*4 + mi][(nh)*2 + ni], 0, 0, 0);     \
  __builtin_amdgcn_s_setprio(0);

  for (;;) {
    if (t == 0) sh = atomicAdd(cnt, 1);
    __syncthreads();
    int rank = sh;
    __syncthreads();
    if (rank >= NITEMS) return;

    // ---- rank -> (bi, bj, k-chunk) ----
    int bi, bj, kt0 = 0, kt1;
    bool zero_item = false, split = false;
    if (rank < NSPLIT) {
      split = true;
      int b_i = TILES - 1, acc2 = 0;
      for (;;) {
        int nch = (b_i + 2) >> 1;              // ceil((bi+1)/2) chunks of 8 steps
        int c = (TILES - b_i) * nch;
        if (rank < acc2 + c) {
          int u = rank - acc2;
          int q = u / nch;
          bj = b_i + q;
          kt0 = (u - q * nch) * CHUNK;
          break;
        }
        acc2 += c; --b_i;
      }
      bi = b_i;
      int nk = (bi + 1) * 4;
      kt1 = nk < kt0 + CHUNK ? nk : kt0 + CHUNK;
    } else if (rank < NUP) {
      int u = rank - NSPLIT;                   // whole tiles, bi 3..0
      int b_i = 3, acc2 = 0;
      for (;;) {
        int c = TILES - b_i;
        if (u < acc2 + c) { bj = b_i + (u - acc2); break; }
        acc2 += c; --b_i;
      }
      bi = b_i; kt1 = (bi + 1) * 4;
    } else {
      zero_item = true;                        // lower tiles bi>bj
      int u = rank - NUP;
      int rr = 1, acc2 = 0;
      while (u >= acc2 + rr) { acc2 += rr; ++rr; }
      bi = rr; bj = u - acc2;
    }

    if (zero_item) {
      float4 z = make_float4(0.f, 0.f, 0.f, 0.f);
#pragma unroll
      for (int i = 0; i < 32; i++) {
        int pos = i * 512 + t;                 // 16384 float4s = 256x256 tile
        int row = pos >> 6, c4 = pos & 63;     // 64 float4 per 256-col row
        *reinterpret_cast<float4*>(C + (long)(bi * BM + row) * N + bj * BM + c4 * 4) = z;
      }
      continue;
    }

    int row0 = bi * BM, col0 = bj * BM;
    int ns = kt1 - kt0;

    const unsigned short* gA = Abf + (long)(row0 + r) * N + cks * 8;
    const unsigned short* gB = Bt  + (long)(col0 + r) * N + cks * 8;

    f32x4 acc[8][4];
#pragma unroll
    for (int m = 0; m < 8; m++)
#pragma unroll
      for (int n = 0; n < 4; n++)
        acc[m][n] = (f32x4){0.f, 0.f, 0.f, 0.f};

    // prologue: A-j0 pair, all B, A-j1 pair; vmcnt(2) -> A-j0 + all B resident
    STA(0, 0, 0, kt0); STA(0, 1, 0, kt0);
    STB(0, 0, 0, kt0); STB(0, 0, 1, kt0); STB(0, 1, 0, kt0); STB(0, 1, 1, kt0);
    STA(0, 0, 1, kt0); STA(0, 1, 1, kt0);
    asm volatile("s_waitcnt vmcnt(2)" ::: "memory");
    __builtin_amdgcn_s_barrier();

    for (int s = 0; s < ns; ++s) {
      int buf = s & 1, nb = buf ^ 1;
      bool more = (s + 1 < ns);
      int ktn = kt0 + s + 1;
      const unsigned short* bufA = &lA[buf][0];
      const unsigned short* bufB = &lB[buf][0];
      s16x8 af[4][2], bf[2][2];

      // ---- P1: Q(0,0) ----
#pragma unroll
      for (int mi = 0; mi < 4; mi++) { af[mi][0] = LDA(0, mi, 0); af[mi][1] = LDA(0, mi, 1); }
#pragma unroll
      for (int ni = 0; ni < 2; ni++) { bf[ni][0] = LDB(0, ni, 0); bf[ni][1] = LDB(0, ni, 1); }
      if (more) { STA(nb, 0, 0, ktn); STA(nb, 1, 0, ktn); }
      __builtin_amdgcn_s_barrier();
      MMQ(0, 0);
      __builtin_amdgcn_s_barrier();

      // ---- P2: Q(0,1) ---- vmcnt(4) -> this tile's A-j1 resident (for P3)
#pragma unroll
      for (int ni = 0; ni < 2; ni++) { bf[ni][0] = LDB(1, ni, 0); bf[ni][1] = LDB(1, ni, 1); }
      if (more) {
        STB(nb, 0, 0, ktn); STB(nb, 0, 1, ktn);
        asm volatile("s_waitcnt vmcnt(4)" ::: "memory");
      } else {
        asm volatile("s_waitcnt vmcnt(0)" ::: "memory");
      }
      __builtin_amdgcn_s_barrier();
      MMQ(0, 1);
      __builtin_amdgcn_s_barrier();

      // ---- P3: Q(1,0) ----
#pragma unroll
      for (int mi = 0; mi < 4; mi++) { af[mi][0] = LDA(1, mi, 0); af[mi][1] = LDA(1, mi, 1); }
#pragma unroll
      for (int ni = 0; ni < 2; ni++) { bf[ni][0] = LDB(0, ni, 0); bf[ni][1] = LDB(0, ni, 1); }
      if (more) { STB(nb, 1, 0, ktn); STB(nb, 1, 1, ktn); }
      __builtin_amdgcn_s_barrier();
      MMQ(1, 0);
      __builtin_amdgcn_s_barrier();

      // ---- P4: Q(1,1) ---- vmcnt(2) -> next tile's A-j0 + all B resident
#pragma unroll
      for (int ni = 0; ni < 2; ni++) { bf[ni][0] = LDB(1, ni, 0); bf[ni][1] = LDB(1, ni, 1); }
      if (more) {
        STA(nb, 0, 1, ktn); STA(nb, 1, 1, ktn);
        asm volatile("s_waitcnt vmcnt(2)" ::: "memory");
      }
      __builtin_amdgcn_s_barrier();
      MMQ(1, 1);
      __builtin_amdgcn_s_barrier();
    }

    // ---- epilogue: C/D layout col=lane&15, row=(lane>>4)*4+reg ----
    bool diag = (bi == bj);
    if (!split || kt0 == 0) {
      // owner chunk / whole tile: plain store with diag mask
#pragma unroll
      for (int m = 0; m < 8; m++) {
        int rowb = row0 + wr * 128 + m * 16 + l4 * 4;
#pragma unroll
        for (int n = 0; n < 4; n++) {
          int col = col0 + wc * 64 + n * 16 + l15;
#pragma unroll
          for (int rr2 = 0; rr2 < 4; rr2++) {
            int row = rowb + rr2;
            float v = acc[m][n][rr2];
            if (diag && row > col) v = 0.f;
            C[(long)row * N + col] = v;
          }
        }
      }
      if (split) {
        __threadfence();                       // each thread's stores visible
        __syncthreads();                       // ALL threads' stores fenced
        if (t == 0) atomicExch(&flags[bi * 16 + bj], 1);
      }
    } else {
      // non-owner chunk: wait for owner's base store, then accumulate.
      // Deadlock-free: owner rank < this rank, so owner was grabbed earlier
      // by a resident worker and its path never waits.
      if (t == 0) {
        while (atomicAdd(&flags[bi * 16 + bj], 0) == 0) __builtin_amdgcn_s_sleep(8);
      }
      __syncthreads();
#pragma unroll
      for (int m = 0; m < 8; m++) {
        int rowb = row0 + wr * 128 + m * 16 + l4 * 4;
#pragma unroll
        for (int n = 0; n < 4; n++) {
          int col = col0 + wc * 64 + n * 16 + l15;
#pragma unroll
          for (int rr2 = 0; rr2 < 4; rr2++) {
            int row = rowb + rr2;
            if (!(diag && row > col)) atomicAdd(&C[(long)row * N + col], acc[m][n][rr2]);
          }
        }
      }
    }
  }
#undef STA
#undef STB
#undef LDA
#undef LDB
#undef MMQ
}

extern "C" void kernel_launch(void* const* d_in, const int* in_sizes, int n_in,
                              void* d_out, int out_size, void* d_ws, size_t ws_size,
                              hipStream_t stream) {
  const float* A = (const float*)d_in[0];
  const float* B = (const float*)d_in[1];
  float* C = (float*)d_out;
  unsigned short* Abf = (unsigned short*)d_ws;
  unsigned short* Bt = Abf + (size_t)N * N;
  // counter + flags in a Bt hole: col-tile 0 only needs k<256; col=0, k>=2048
  // is never written by prep nor read by trigemm staging.
  int* cnt = (int*)(Bt + 2048);
  int* flags = (int*)(Bt + 2052);   // 256 ints

  prep<<<dim3(12288), dim3(256), 0, stream>>>(A, B, Abf, Bt, cnt, flags);
  trigemm<<<dim3(NWORKERS), dim3(512), 0, stream>>>(Abf, Bt, C, cnt, flags);
}

// Round 11
// 131.096 us; speedup vs baseline: 1.0726x; 1.0726x over previous
//
#include <hip/hip_runtime.h>
#include <stdint.h>

#define N 4096
#define BM 256
#define BK 64
#define TILES 16
#define NSPLIT 271   // chunked items, bi>=3 (chunks <=13 k64-steps, atomic)
#define NITEMS 316   // + whole tiles bi 2..0 (14+15+16, plain store)
#define NWORKERS 256 // 1 block/CU (128KB LDS)

typedef __attribute__((ext_vector_type(8))) short s16x8;
typedef __attribute__((ext_vector_type(4))) float f32x4;

// round-to-nearest-even fp32 -> bf16
__device__ __forceinline__ unsigned short f2bf(float f) {
  union { float f; unsigned int u; } c; c.f = f;
  unsigned int u = c.u;
  unsigned int r = (u + 0x7fffu + ((u >> 16) & 1u)) >> 16;
  return (unsigned short)r;
}

__device__ __forceinline__ void gld16(const void* g, void* l) {
  __builtin_amdgcn_global_load_lds(
      (const __attribute__((address_space(1))) unsigned int*)g,
      (__attribute__((address_space(3))) unsigned int*)l,
      16, 0, 0);
}

// Fused prepass:
//  [0,13312):      C rows [768,4096) zeroed (atomicAdd targets, bi>=3)
//  [13312,13504):  C lower tiles (1,0)(2,0)(2,1) zeroed
//  [13504,17600):  B -> triu-masked bf16 transposed (256-granular k-bound)
//  [17600,25792):  A -> tril-masked bf16 (256-granular k-bound; written last = freshest in L3)
// Block 0 resets the work counter.
__global__ void prep(const float* __restrict__ A, const float* __restrict__ B,
                     unsigned short* __restrict__ Abf, unsigned short* __restrict__ Bt,
                     float* __restrict__ C, int* __restrict__ cnt) {
  int bid = blockIdx.x;
  int t = threadIdx.x;
  if (bid == 0 && t == 0) *cnt = 0;   // prep completes before trigemm (stream order)
  if (bid < 13312) {
    // ---- C-zero: rows [768,4096), 16B/thread ----
    long idx = (long)bid * 256 + t;
    float4 z = make_float4(0.f, 0.f, 0.f, 0.f);
    *reinterpret_cast<float4*>(C + (long)768 * N + idx * 4) = z;
  } else if (bid < 13504) {
    // ---- C-zero: lower tiles (1,0),(2,0),(2,1) ----
    int idx = bid - 13312;
    int tl = idx >> 6, sub = idx & 63;
    int bi = (tl == 0) ? 1 : 2;
    int bj = (tl <= 1) ? 0 : 1;
    int row = bi * 256 + (sub << 2) + (t >> 6);
    int col = bj * 256 + (t & 63) * 4;
    float4 z = make_float4(0.f, 0.f, 0.f, 0.f);
    *reinterpret_cast<float4*>(C + (long)row * N + col) = z;
  } else if (bid < 17600) {
    // ---- B path: 64x64 tile transpose with triu mask ----
    int b2 = bid - 13504;
    int k0 = (b2 & 63) * 64;
    int c0 = (b2 >> 6) * 64;
    int cj = c0 >> 8;                             // 256-col tile
    if (k0 >= ((cj + 1) << 8)) return;            // never read by trigemm
    if (k0 > c0 + 63) {
      ushort4 z = make_ushort4(0, 0, 0, 0);
#pragma unroll
      for (int p = 0; p < 4; p++) {
        int cl = p * 16 + (t >> 4);
        int kl = (t & 15) * 4;
        *reinterpret_cast<ushort4*>(Bt + (long)(c0 + cl) * N + k0 + kl) = z;
      }
      return;
    }
    __shared__ unsigned short lds[64][72];        // +8 pad breaks transpose conflicts
#pragma unroll
    for (int p = 0; p < 4; p++) {
      int kl = p * 16 + (t >> 4);
      int cl = (t & 15) * 4;
      float4 v = *reinterpret_cast<const float4*>(B + (long)(k0 + kl) * N + c0 + cl);
      float vs[4] = {v.x, v.y, v.z, v.w};
#pragma unroll
      for (int i = 0; i < 4; i++)
        lds[kl][cl + i] = (k0 + kl <= c0 + cl + i) ? f2bf(vs[i]) : (unsigned short)0;
    }
    __syncthreads();
#pragma unroll
    for (int p = 0; p < 4; p++) {
      int cl = p * 16 + (t >> 4);
      int kl = (t & 15) * 4;
      ushort4 o;
      o.x = lds[kl + 0][cl]; o.y = lds[kl + 1][cl];
      o.z = lds[kl + 2][cl]; o.w = lds[kl + 3][cl];
      *reinterpret_cast<ushort4*>(Bt + (long)(c0 + cl) * N + k0 + kl) = o;
    }
  } else {
    // ---- A path: one block = half a row (2048 elems), 8 elems/thread ----
    long base = (long)(bid - 17600) * 2048 + (long)t * 8;
    int row = (int)(base >> 12);
    int k0 = (int)(base & 4095);
    int bound = ((row >> 8) + 1) << 8;            // 256-granular: first k never read
    if (k0 >= bound) return;
    if (k0 > row) {
      uint4 z = make_uint4(0u, 0u, 0u, 0u);
      *reinterpret_cast<uint4*>(Abf + base) = z;
      return;
    }
    const float4* src = reinterpret_cast<const float4*>(A + base);
    float4 v0 = src[0], v1 = src[1];
    float vs[8] = {v0.x, v0.y, v0.z, v0.w, v1.x, v1.y, v1.z, v1.w};
    unsigned int w[4];
#pragma unroll
    for (int i = 0; i < 4; i++) {
      unsigned int lo = (k0 + 2*i     <= row) ? f2bf(vs[2*i])     : 0u;
      unsigned int hi = (k0 + 2*i + 1 <= row) ? f2bf(vs[2*i + 1]) : 0u;
      w[i] = lo | (hi << 16);
    }
    uint4 o; o.x = w[0]; o.y = w[1]; o.z = w[2]; o.w = w[3];
    *reinterpret_cast<uint4*>(Abf + base) = o;
  }
}

// Triangular bf16 MFMA GEMM, 256x256 tile, 8-wave, 4-phase K-loop.
// Balanced LPT queue (chunks <=13 steps, 316 items). bi>=3 chunks atomicAdd
// onto prep-zeroed C; bi<=2 whole tiles plain-store. Deep vmcnt schedule:
// all next-tile pieces issued by P2; vmcnt(8)@P2 (cur A1, 4-phase cover),
// vmcnt(2)@P4 (next P1 pieces, 2-3 phase cover). Invariant: 2 outstanding.
__global__ __launch_bounds__(512, 2) void trigemm(
    const unsigned short* __restrict__ Abf,
    const unsigned short* __restrict__ Bt,
    float* __restrict__ C, int* __restrict__ cnt) {
  __shared__ unsigned short lA[2][BM * BK];  // 64 KB, XOR-swizzled rows of 128B
  __shared__ unsigned short lB[2][BM * BK];  // 64 KB
  __shared__ int sh;

  int t = threadIdx.x;
  int lane = t & 63, wave = t >> 6;
  int wr = wave >> 2, wc = wave & 3;          // 2M x 4N wave grid
  int l15 = lane & 15, l4 = lane >> 4;
  int sw7 = l15 & 7;
  int c0w = (l4 ^ sw7) * 8;                   // swizzled chunk, kk=0
  int c1w = ((4 + l4) ^ sw7) * 8;             // swizzled chunk, kk=1

  // staging: thread t -> row r (0..63 within 64-row piece), 16B chunk ck
  int r = t >> 3, ck = t & 7;
  int cks = ck ^ (r & 7);                     // inverse-swizzled source chunk
  unsigned short* dA = &lA[0][0] + r * BK + ck * 8;  // linear: base + t*16B
  unsigned short* dB = &lB[0][0] + r * BK + ck * 8;

#define STA(buf, h, j, kt) gld16(gA + (long)((h)*128 + (j)*64) * N + (long)(kt) * BK, \
                                 dA + (buf) * (BM * BK) + ((h)*128 + (j)*64) * BK)
#define STB(buf, h, j, kt) gld16(gB + (long)((h)*128 + (j)*64) * N + (long)(kt) * BK, \
                                 dB + (buf) * (BM * BK) + ((h)*128 + (j)*64) * BK)
#define LDA(mh, mi, kk) (*reinterpret_cast<const s16x8*>( \
    &bufA[(wr * 128 + (mh) * 64 + (mi) * 16 + l15) * BK + ((kk) ? c1w : c0w)]))
#define LDB(nh, ni, kk) (*reinterpret_cast<const s16x8*>( \
    &bufB[(wc * 64 + (nh) * 32 + (ni) * 16 + l15) * BK + ((kk) ? c1w : c0w)]))
#define MMQ(mh, nh)                                                          \
  __builtin_amdgcn_s_setprio(1);                                             \
  _Pragma("unroll") for (int mi = 0; mi < 4; mi++)                           \
  _Pragma("unroll") for (int ni = 0; ni < 2; ni++)                           \
  _Pragma("unroll") for (int kk = 0; kk < 2; kk++)                           \
    acc[(mh)*4 + mi][(nh)*2 + ni] = __builtin_amdgcn_mfma_f32_16x16x32_bf16( \
        af[mi][kk], bf[ni][kk], acc[(mh)*4 + mi][(nh)*2 + ni], 0, 0, 0);     \
  __builtin_amdgcn_s_setprio(0);

  for (;;) {
    if (t == 0) sh = atomicAdd(cnt, 1);
    __syncthreads();
    int rank = sh;
    __syncthreads();
    if (rank >= NITEMS) return;

    // ---- rank -> (bi, bj, k-chunk), heavy-first (bi descending) ----
    int bi, bj, kt0 = 0, kt1;
    bool use_atomic;
    if (rank < NSPLIT) {
      use_atomic = true;
      int b_i = TILES - 1, acc2 = 0;
      for (;;) {
        int nk = 4 * (b_i + 1);
        int nch = (nk + 12) / 13;              // ceil(nk/13) chunks per tile
        int c = (TILES - b_i) * nch;
        if (rank < acc2 + c) {
          int u = rank - acc2;
          int q = u / nch;
          bj = b_i + q;
          int ci = u - q * nch;
          int cs = (nk + nch - 1) / nch;       // chunk size
          kt0 = ci * cs;
          kt1 = nk < kt0 + cs ? nk : kt0 + cs;
          break;
        }
        acc2 += c; --b_i;
      }
      bi = b_i;
    } else {
      use_atomic = false;                      // whole tiles bi 2..0, plain store
      int u = rank - NSPLIT;
      if (u < 14)      { bi = 2; bj = 2 + u; }
      else if (u < 29) { bi = 1; bj = 1 + (u - 14); }
      else             { bi = 0; bj = u - 29; }
      kt1 = 4 * (bi + 1);
    }

    int row0 = bi * BM, col0 = bj * BM;
    int ns = kt1 - kt0;

    const unsigned short* gA = Abf + (long)(row0 + r) * N + cks * 8;
    const unsigned short* gB = Bt  + (long)(col0 + r) * N + cks * 8;

    f32x4 acc[8][4];
#pragma unroll
    for (int m = 0; m < 8; m++)
#pragma unroll
      for (int n = 0; n < 4; n++)
        acc[m][n] = (f32x4){0.f, 0.f, 0.f, 0.f};

    // prologue: A-j0 pair, all B, A-j1 pair; vmcnt(2) -> A-j0 + all B resident
    STA(0, 0, 0, kt0); STA(0, 1, 0, kt0);
    STB(0, 0, 0, kt0); STB(0, 0, 1, kt0); STB(0, 1, 0, kt0); STB(0, 1, 1, kt0);
    STA(0, 0, 1, kt0); STA(0, 1, 1, kt0);
    asm volatile("s_waitcnt vmcnt(2)" ::: "memory");
    __builtin_amdgcn_s_barrier();

    for (int s = 0; s < ns; ++s) {
      int buf = s & 1, nb = buf ^ 1;
      bool more = (s + 1 < ns);
      int ktn = kt0 + s + 1;
      const unsigned short* bufA = &lA[buf][0];
      const unsigned short* bufB = &lB[buf][0];
      s16x8 af[4][2], bf[2][2];

      // ---- P1: Q(0,0) ---- issue next A-j0 pair + B(0,*)
#pragma unroll
      for (int mi = 0; mi < 4; mi++) { af[mi][0] = LDA(0, mi, 0); af[mi][1] = LDA(0, mi, 1); }
#pragma unroll
      for (int ni = 0; ni < 2; ni++) { bf[ni][0] = LDB(0, ni, 0); bf[ni][1] = LDB(0, ni, 1); }
      if (more) { STA(nb, 0, 0, ktn); STA(nb, 1, 0, ktn); STB(nb, 0, 0, ktn); STB(nb, 0, 1, ktn); }
      __builtin_amdgcn_s_barrier();
      MMQ(0, 0);
      __builtin_amdgcn_s_barrier();

      // ---- P2: Q(0,1) ---- issue next B(1,*) + A-j1 pair; wait cur A-j1
#pragma unroll
      for (int ni = 0; ni < 2; ni++) { bf[ni][0] = LDB(1, ni, 0); bf[ni][1] = LDB(1, ni, 1); }
      if (more) {
        STB(nb, 1, 0, ktn); STB(nb, 1, 1, ktn); STA(nb, 0, 1, ktn); STA(nb, 1, 1, ktn);
        asm volatile("s_waitcnt vmcnt(8)" ::: "memory");  // cur A(0,1),A(1,1) resident
      } else {
        asm volatile("s_waitcnt vmcnt(0)" ::: "memory");
      }
      __builtin_amdgcn_s_barrier();
      MMQ(0, 1);
      __builtin_amdgcn_s_barrier();

      // ---- P3: Q(1,0) ----
#pragma unroll
      for (int mi = 0; mi < 4; mi++) { af[mi][0] = LDA(1, mi, 0); af[mi][1] = LDA(1, mi, 1); }
#pragma unroll
      for (int ni = 0; ni < 2; ni++) { bf[ni][0] = LDB(0, ni, 0); bf[ni][1] = LDB(0, ni, 1); }
      __builtin_amdgcn_s_barrier();
      MMQ(1, 0);
      __builtin_amdgcn_s_barrier();

      // ---- P4: Q(1,1) ---- wait next tile's P1 pieces (issued P1/P2, 2-3 phases ago)
#pragma unroll
      for (int ni = 0; ni < 2; ni++) { bf[ni][0] = LDB(1, ni, 0); bf[ni][1] = LDB(1, ni, 1); }
      if (more) asm volatile("s_waitcnt vmcnt(2)" ::: "memory");
      __builtin_amdgcn_s_barrier();
      MMQ(1, 1);
      __builtin_amdgcn_s_barrier();
    }

    // ---- epilogue: C/D layout col=lane&15, row=(lane>>4)*4+reg ----
    bool diag = (bi == bj);
    if (use_atomic) {
#pragma unroll
      for (int m = 0; m < 8; m++) {
        int rowb = row0 + wr * 128 + m * 16 + l4 * 4;
#pragma unroll
        for (int n = 0; n < 4; n++) {
          int col = col0 + wc * 64 + n * 16 + l15;
#pragma unroll
          for (int rr2 = 0; rr2 < 4; rr2++) {
            int row = rowb + rr2;
            if (!(diag && row > col)) atomicAdd(&C[(long)row * N + col], acc[m][n][rr2]);
          }
        }
      }
    } else {
#pragma unroll
      for (int m = 0; m < 8; m++) {
        int rowb = row0 + wr * 128 + m * 16 + l4 * 4;
#pragma unroll
        for (int n = 0; n < 4; n++) {
          int col = col0 + wc * 64 + n * 16 + l15;
#pragma unroll
          for (int rr2 = 0; rr2 < 4; rr2++) {
            int row = rowb + rr2;
            float v = acc[m][n][rr2];
            if (diag && row > col) v = 0.f;
            C[(long)row * N + col] = v;
          }
        }
      }
    }
  }
#undef STA
#undef STB
#undef LDA
#undef LDB
#undef MMQ
}

extern "C" void kernel_launch(void* const* d_in, const int* in_sizes, int n_in,
                              void* d_out, int out_size, void* d_ws, size_t ws_size,
                              hipStream_t stream) {
  const float* A = (const float*)d_in[0];
  const float* B = (const float*)d_in[1];
  float* C = (float*)d_out;
  unsigned short* Abf = (unsigned short*)d_ws;
  unsigned short* Bt = Abf + (size_t)N * N;
  // counter in a Bt hole: col-tile 0 only needs k<256; col=0, k=2048 is
  // never written by prep nor read by trigemm staging.
  int* cnt = (int*)(Bt + 2048);

  prep<<<dim3(25792), dim3(256), 0, stream>>>(A, B, Abf, Bt, C, cnt);
  trigemm<<<dim3(NWORKERS), dim3(512), 0, stream>>>(Abf, Bt, C, cnt);
}

// Round 12
// 101.104 us; speedup vs baseline: 1.3907x; 1.2966x over previous
//
#include <hip/hip_runtime.h>
#include <stdint.h>

#define N 4096
#define BM 256
#define BK 32
#define TILES 16
#define NSPLIT 202   // bi>=4 chunk items (K-span 1024 = 32 k32-steps, atomic)
#define NITEMS 260   // + whole tiles bi 3..0 (13+14+15+16, plain store)
#define NWORKERS 256 // 1 block/CU (128KB LDS)

typedef __attribute__((ext_vector_type(8))) short s16x8;
typedef __attribute__((ext_vector_type(4))) float f32x4;

// round-to-nearest-even fp32 -> bf16
__device__ __forceinline__ unsigned short f2bf(float f) {
  union { float f; unsigned int u; } c; c.f = f;
  unsigned int u = c.u;
  unsigned int r = (u + 0x7fffu + ((u >> 16) & 1u)) >> 16;
  return (unsigned short)r;
}

__device__ __forceinline__ void gld16(const void* g, void* l) {
  __builtin_amdgcn_global_load_lds(
      (const __attribute__((address_space(1))) unsigned int*)g,
      (__attribute__((address_space(3))) unsigned int*)l,
      16, 0, 0);
}

// Fused prepass (R8's, measured):
//  [0,12288):      C rows [1024,4096) zeroed (atomic targets, bi>=4)
//  [12288,12672):  C lower tiles (1,0)(2,0)(2,1)(3,0)(3,1)(3,2) zeroed
//  [12672,16768):  B -> triu-masked bf16 transposed (256-granular k-bound)
//  [16768,24960):  A -> tril-masked bf16 (256-granular k-bound)
__global__ void prep(const float* __restrict__ A, const float* __restrict__ B,
                     unsigned short* __restrict__ Abf, unsigned short* __restrict__ Bt,
                     float* __restrict__ C, int* __restrict__ cnt) {
  int bid = blockIdx.x;
  int t = threadIdx.x;
  if (bid == 0 && t == 0) *cnt = 0;   // prep completes before trigemm (stream order)
  if (bid < 12288) {
    long idx = (long)bid * 256 + t;
    float4 z = make_float4(0.f, 0.f, 0.f, 0.f);
    *reinterpret_cast<float4*>(C + (long)1024 * N + idx * 4) = z;
  } else if (bid < 12672) {
    int idx = bid - 12288;
    int tl = idx >> 6, sub = idx & 63;
    int bi = 1 + (tl >= 1) + (tl >= 3);
    int bj = tl - ((bi * bi - bi) >> 1);
    int row = bi * 256 + (sub << 2) + (t >> 6);
    int col = bj * 256 + (t & 63) * 4;
    float4 z = make_float4(0.f, 0.f, 0.f, 0.f);
    *reinterpret_cast<float4*>(C + (long)row * N + col) = z;
  } else if (bid < 16768) {
    // ---- B path: 64x64 tile transpose with triu mask ----
    int b2 = bid - 12672;
    int k0 = (b2 & 63) * 64;
    int c0 = (b2 >> 6) * 64;
    int cj = c0 >> 8;                             // 256-col tile
    if (k0 >= ((cj + 1) << 8)) return;            // never read by trigemm
    if (k0 > c0 + 63) {
      ushort4 z = make_ushort4(0, 0, 0, 0);
#pragma unroll
      for (int p = 0; p < 4; p++) {
        int cl = p * 16 + (t >> 4);
        int kl = (t & 15) * 4;
        *reinterpret_cast<ushort4*>(Bt + (long)(c0 + cl) * N + k0 + kl) = z;
      }
      return;
    }
    __shared__ unsigned short lds[64][72];        // +8 pad breaks transpose conflicts
#pragma unroll
    for (int p = 0; p < 4; p++) {
      int kl = p * 16 + (t >> 4);
      int cl = (t & 15) * 4;
      float4 v = *reinterpret_cast<const float4*>(B + (long)(k0 + kl) * N + c0 + cl);
      float vs[4] = {v.x, v.y, v.z, v.w};
#pragma unroll
      for (int i = 0; i < 4; i++)
        lds[kl][cl + i] = (k0 + kl <= c0 + cl + i) ? f2bf(vs[i]) : (unsigned short)0;
    }
    __syncthreads();
#pragma unroll
    for (int p = 0; p < 4; p++) {
      int cl = p * 16 + (t >> 4);
      int kl = (t & 15) * 4;
      ushort4 o;
      o.x = lds[kl + 0][cl]; o.y = lds[kl + 1][cl];
      o.z = lds[kl + 2][cl]; o.w = lds[kl + 3][cl];
      *reinterpret_cast<ushort4*>(Bt + (long)(c0 + cl) * N + k0 + kl) = o;
    }
  } else {
    // ---- A path: one block = half a row (2048 elems), 8 elems/thread ----
    long base = (long)(bid - 16768) * 2048 + (long)t * 8;
    int row = (int)(base >> 12);
    int k0 = (int)(base & 4095);
    int bound = ((row >> 8) + 1) << 8;            // 256-granular: first k never read
    if (k0 >= bound) return;
    if (k0 > row) {
      uint4 z = make_uint4(0u, 0u, 0u, 0u);
      *reinterpret_cast<uint4*>(Abf + base) = z;
      return;
    }
    const float4* src = reinterpret_cast<const float4*>(A + base);
    float4 v0 = src[0], v1 = src[1];
    float vs[8] = {v0.x, v0.y, v0.z, v0.w, v1.x, v1.y, v1.z, v1.w};
    unsigned int w[4];
#pragma unroll
    for (int i = 0; i < 4; i++) {
      unsigned int lo = (k0 + 2*i     <= row) ? f2bf(vs[2*i])     : 0u;
      unsigned int hi = (k0 + 2*i + 1 <= row) ? f2bf(vs[2*i + 1]) : 0u;
      w[i] = lo | (hi << 16);
    }
    uint4 o; o.x = w[0]; o.y = w[1]; o.z = w[2]; o.w = w[3];
    *reinterpret_cast<uint4*>(Abf + base) = o;
  }
}

// Triangular bf16 MFMA GEMM, 256x256 tile, 8-wave, BK=32, DEPTH-3 pipeline:
// 4 LDS buffers; step s stages step s+3 (2 gld16/phase); ONE counted
// vmcnt(8) per step fused into the end-of-step barrier (~6 phases of
// latency cover). 2 phases/step, bf fragments reused across both.
__global__ __launch_bounds__(512, 2) void trigemm(
    const unsigned short* __restrict__ Abf,
    const unsigned short* __restrict__ Bt,
    float* __restrict__ C, int* __restrict__ cnt) {
  __shared__ unsigned short lA[4][BM * BK];  // 4 x 16KB
  __shared__ unsigned short lB[4][BM * BK];  // 4 x 16KB
  __shared__ int sh;

  int t = threadIdx.x;
  int lane = t & 63, wave = t >> 6;
  int wr = wave >> 2, wc = wave & 3;          // 2M x 4N wave grid
  int l15 = lane & 15, l4 = lane >> 4;
  int cw = (l4 ^ ((l15 >> 1) & 3)) * 8;       // swizzled 16B chunk (R7-verified, 0 conflicts)

  // staging: thread t -> row r (0..127 within 128-row piece), 16B chunk ck
  int r = t >> 2, ck = t & 3;
  int cks = ck ^ ((r >> 1) & 3);              // inverse-swizzled source chunk
  unsigned short* dA = &lA[0][0] + r * BK + ck * 8;  // linear: base + t*16B
  unsigned short* dB = &lB[0][0] + r * BK + ck * 8;

#define STA(buf, j, kt) gld16(gA + (long)(j) * 128 * N + (long)(kt) * BK, \
                              dA + (buf) * (BM * BK) + (j) * 128 * BK)
#define STB(buf, j, kt) gld16(gB + (long)(j) * 128 * N + (long)(kt) * BK, \
                              dB + (buf) * (BM * BK) + (j) * 128 * BK)
#define LDA(mh, mi) (*reinterpret_cast<const s16x8*>( \
    &bufA[(wr * 128 + (mh) * 64 + (mi) * 16 + l15) * BK + cw]))
#define LDB(nh, ni) (*reinterpret_cast<const s16x8*>( \
    &bufB[(wc * 64 + (nh) * 32 + (ni) * 16 + l15) * BK + cw]))
#define MM(mh)                                                               \
  __builtin_amdgcn_s_setprio(1);                                             \
  _Pragma("unroll") for (int mi = 0; mi < 4; mi++)                           \
  _Pragma("unroll") for (int n = 0; n < 4; n++)                              \
    acc[(mh)*4 + mi][n] = __builtin_amdgcn_mfma_f32_16x16x32_bf16(           \
        af[mi], bf[n], acc[(mh)*4 + mi][n], 0, 0, 0);                        \
  __builtin_amdgcn_s_setprio(0);

  for (;;) {
    if (t == 0) sh = atomicAdd(cnt, 1);
    __syncthreads();
    int rank = sh;
    __syncthreads();
    if (rank >= NITEMS) return;

    // ---- rank -> (bi, bj, k32-chunk), heavy-first ----
    int bi, bj, kt0 = 0, kt1;
    bool use_atomic;
    if (rank < NSPLIT) {
      use_atomic = true;
      int b_i = TILES - 1, acc2 = 0;
      for (;;) {
        int nch = (b_i + 4) >> 2;              // ceil((bi+1)/4) chunks (span 1024)
        int c = (TILES - b_i) * nch;
        if (rank < acc2 + c) {
          int u = rank - acc2;
          int q = u / nch;
          bj = b_i + q;
          kt0 = (u - q * nch) * 32;            // k32 units
          break;
        }
        acc2 += c; --b_i;
      }
      bi = b_i;
      int nk = (bi + 1) * 8;
      kt1 = nk < kt0 + 32 ? nk : kt0 + 32;
    } else {
      use_atomic = false;                      // whole tiles bi 3..0
      int u = rank - NSPLIT;
      if (u < 13)      { bi = 3; bj = 3 + u; }
      else if (u < 27) { bi = 2; bj = 2 + (u - 13); }
      else if (u < 42) { bi = 1; bj = 1 + (u - 27); }
      else             { bi = 0; bj = u - 42; }
      kt1 = (bi + 1) * 8;
    }

    int row0 = bi * BM, col0 = bj * BM;
    int ns = kt1 - kt0;                        // always >= 8

    const unsigned short* gA = Abf + (long)(row0 + r) * N + cks * 8;
    const unsigned short* gB = Bt  + (long)(col0 + r) * N + cks * 8;

    f32x4 acc[8][4];
#pragma unroll
    for (int m = 0; m < 8; m++)
#pragma unroll
      for (int n = 0; n < 4; n++)
        acc[m][n] = (f32x4){0.f, 0.f, 0.f, 0.f};

    // prologue: stage steps 0,1,2 (4 pieces each: A0,A1,B0,B1)
#pragma unroll
    for (int p = 0; p < 3; p++) {
      STA(p, 0, kt0 + p); STA(p, 1, kt0 + p);
      STB(p, 0, kt0 + p); STB(p, 1, kt0 + p);
    }
    asm volatile("s_waitcnt vmcnt(8)" ::: "memory");  // step-0 pieces resident
    __builtin_amdgcn_s_barrier();

    for (int s = 0; s < ns; ++s) {
      int buf = s & 3;
      bool stage = (s + 3 < ns);
      int nb = (s + 3) & 3, ktn = kt0 + s + 3;
      const unsigned short* bufA = &lA[buf][0];
      const unsigned short* bufB = &lB[buf][0];
      s16x8 af[4], bf[4];

      // ---- P1 (mh=0): read af0 + all bf; stage next A pieces ----
#pragma unroll
      for (int mi = 0; mi < 4; mi++) af[mi] = LDA(0, mi);
#pragma unroll
      for (int nh = 0; nh < 2; nh++)
#pragma unroll
        for (int ni = 0; ni < 2; ni++) bf[nh * 2 + ni] = LDB(nh, ni);
      if (stage) { STA(nb, 0, ktn); STA(nb, 1, ktn); }
      __builtin_amdgcn_s_barrier();
      MM(0);
      __builtin_amdgcn_s_barrier();

      // ---- P2 (mh=1): read af1, reuse bf; stage next B pieces ----
#pragma unroll
      for (int mi = 0; mi < 4; mi++) af[mi] = LDA(1, mi);
      if (stage) { STB(nb, 0, ktn); STB(nb, 1, ktn); }
      __builtin_amdgcn_s_barrier();
      MM(1);
      // fused end-of-step wait: next step's pieces must be resident after
      // this barrier. rem = steps whose pieces may stay outstanding.
      if (s + 1 < ns) {
        int rem = ns - 2 - s;
        if (rem >= 2)      asm volatile("s_waitcnt vmcnt(8)" ::: "memory");
        else if (rem == 1) asm volatile("s_waitcnt vmcnt(4)" ::: "memory");
        else               asm volatile("s_waitcnt vmcnt(0)" ::: "memory");
      }
      __builtin_amdgcn_s_barrier();
    }

    // ---- epilogue: C/D layout col=lane&15, row=(lane>>4)*4+reg ----
    bool diag = (bi == bj);
    if (use_atomic) {
#pragma unroll
      for (int m = 0; m < 8; m++) {
        int rowb = row0 + wr * 128 + m * 16 + l4 * 4;
#pragma unroll
        for (int n = 0; n < 4; n++) {
          int col = col0 + wc * 64 + n * 16 + l15;
#pragma unroll
          for (int rr2 = 0; rr2 < 4; rr2++) {
            int row = rowb + rr2;
            if (!(diag && row > col)) atomicAdd(&C[(long)row * N + col], acc[m][n][rr2]);
          }
        }
      }
    } else {
#pragma unroll
      for (int m = 0; m < 8; m++) {
        int rowb = row0 + wr * 128 + m * 16 + l4 * 4;
#pragma unroll
        for (int n = 0; n < 4; n++) {
          int col = col0 + wc * 64 + n * 16 + l15;
#pragma unroll
          for (int rr2 = 0; rr2 < 4; rr2++) {
            int row = rowb + rr2;
            float v = acc[m][n][rr2];
            if (diag && row > col) v = 0.f;
            C[(long)row * N + col] = v;
          }
        }
      }
    }
  }
#undef STA
#undef STB
#undef LDA
#undef LDB
#undef MM
}

extern "C" void kernel_launch(void* const* d_in, const int* in_sizes, int n_in,
                              void* d_out, int out_size, void* d_ws, size_t ws_size,
                              hipStream_t stream) {
  const float* A = (const float*)d_in[0];
  const float* B = (const float*)d_in[1];
  float* C = (float*)d_out;
  unsigned short* Abf = (unsigned short*)d_ws;
  unsigned short* Bt = Abf + (size_t)N * N;
  // counter in a Bt hole: col-tile 0 only needs k<256; col=0, k=2048 is
  // never written by prep nor read by trigemm staging.
  int* cnt = (int*)(Bt + 2048);

  prep<<<dim3(24960), dim3(256), 0, stream>>>(A, B, Abf, Bt, C, cnt);
  trigemm<<<dim3(NWORKERS), dim3(512), 0, stream>>>(Abf, Bt, C, cnt);
}